// Round 1
// baseline (351.307 us; speedup 1.0000x reference)
//
#include <hip/hip_runtime.h>

typedef __bf16 bf16;
typedef __bf16 bf16x8 __attribute__((ext_vector_type(8)));
typedef __bf16 bf16x4 __attribute__((ext_vector_type(4)));
typedef float  f32x4  __attribute__((ext_vector_type(4)));
typedef unsigned int u32;
typedef unsigned int u32x2 __attribute__((ext_vector_type(2)));
typedef unsigned int u32x4 __attribute__((ext_vector_type(4)));
typedef unsigned short u16;

#define MFMA16(a, b, c) __builtin_amdgcn_mfma_f32_16x16x32_bf16((a), (b), (c), 0, 0, 0)

// B=1, S=128, R=256, C=256, H=8, Ca=32.  M = S*R = 32768, K = 256.

// ---- async global->LDS, 16 B per lane (guide §5: width=16) ----
typedef __attribute__((address_space(3))) u32 lds_u32;
typedef const __attribute__((address_space(1))) u32 glob_u32;
__device__ __forceinline__ void gll16(const void* g, void* l) {
    __builtin_amdgcn_global_load_lds((glob_u32*)g, (lds_u32*)l, 16, 0, 0);
}

// pack two f32 -> one u32 of 2 bf16 (lo, hi); compiler emits v_cvt_pk_bf16_f32
__device__ __forceinline__ u32 pk2(float lo, float hi) {
    u16 a = __builtin_bit_cast(u16, (bf16)lo);
    u16 b = __builtin_bit_cast(u16, (bf16)hi);
    return ((u32)b << 16) | (u32)a;
}

// ================= prep: bf16 convert + weight/bias transposes =================
__global__ __launch_bounds__(256) void prep_kernel(
    const float* __restrict__ q, const float* __restrict__ kv,
    const float* __restrict__ bias,
    const float* __restrict__ w_q, const float* __restrict__ w_k,
    const float* __restrict__ w_v, const float* __restrict__ w_g,
    const float* __restrict__ w_o,
    bf16* __restrict__ qbf, bf16* __restrict__ kvbf, float* __restrict__ biasT,
    bf16* __restrict__ Wqg, bf16* __restrict__ Wkv, bf16* __restrict__ Wo)
{
    const float norm = 0.17677669529663687f;  // 1/sqrt(32) baked into Wq
    const int gid = blockIdx.x * 256 + threadIdx.x;
    const int gsz = gridDim.x * 256;

    // q/kv -> bf16, 8 elems per unit (vectorized)
    for (int u = gid; u < 2097152; u += gsz) {
        const float* src; bf16* dst;
        if (u < 1048576) { src = q + (size_t)u * 8;            dst = qbf  + (size_t)u * 8; }
        else             { src = kv + (size_t)(u - 1048576)*8; dst = kvbf + (size_t)(u - 1048576)*8; }
        float4 x0 = *(const float4*)(src);
        float4 x1 = *(const float4*)(src + 4);
        bf16x8 t;
        t[0]=(bf16)x0.x; t[1]=(bf16)x0.y; t[2]=(bf16)x0.z; t[3]=(bf16)x0.w;
        t[4]=(bf16)x1.x; t[5]=(bf16)x1.y; t[6]=(bf16)x1.z; t[7]=(bf16)x1.w;
        *(bf16x8*)dst = t;
    }
    // biasT[h][q][k] <- bias[q][k][h]  (coalesced writes)
    for (int u = gid; u < 524288; u += gsz) {
        int h = u >> 16, qq = (u >> 8) & 255, kk = u & 255;
        biasT[u] = bias[(((qq << 8) + kk) << 3) + h];
    }
    // Wqg[n][k]: n<256 -> w_q[k][n]*norm ; else w_g[k][n-256]
    for (int u = gid; u < 131072; u += gsz) {
        int n = u >> 8, k = u & 255;
        float v = (n < 256) ? w_q[k * 256 + n] * norm : w_g[k * 256 + (n - 256)];
        Wqg[u] = (bf16)v;
    }
    // Wkv[n][k]: n<256 -> w_k[k][n] ; else w_v[k][n-256]
    for (int u = gid; u < 131072; u += gsz) {
        int n = u >> 8, k = u & 255;
        float v = (n < 256) ? w_k[k * 256 + n] : w_v[k * 256 + (n - 256)];
        Wkv[u] = (bf16)v;
    }
    // Wo[n][k] = w_o[k][n]   ([H*Ca][C] -> [C][H*Ca])
    for (int u = gid; u < 65536; u += gsz) {
        int n = u >> 8, k = u & 255;
        Wo[u] = (bf16)w_o[k * 256 + n];
    }
}

// ================= tiled GEMM core: C[M][ntot] = A[M][256] @ Bw[ntot][256]^T ===
// 128x128 tile, 256 threads (4 waves, each 64x64), BK=32, global_load_lds staging.
template<bool F32OUT>
__device__ __forceinline__ void gemm_core(
    const bf16* __restrict__ A, const bf16* __restrict__ Bw,
    bf16* __restrict__ Cb, float* __restrict__ Cf, const float* __restrict__ bo,
    int m0, int n0, int ntot)
{
    __shared__ __align__(16) bf16 As[128 * 32];
    __shared__ __align__(16) bf16 Bs[128 * 32];

    const int tid  = threadIdx.x;
    const int lane = tid & 63, wave = tid >> 6;
    const int quad = lane >> 4, lc = lane & 15;
    const int wr = wave >> 1, wc = wave & 1;

    const int r0 = tid >> 2, p0 = tid & 3;
    const bf16* gA0 = A  + (size_t)(m0 + r0) * 256 + p0 * 8;
    const bf16* gA1 = A  + (size_t)(m0 + 64 + r0) * 256 + p0 * 8;
    const bf16* gB0 = Bw + (size_t)(n0 + r0) * 256 + p0 * 8;
    const bf16* gB1 = Bw + (size_t)(n0 + 64 + r0) * 256 + p0 * 8;
    bf16* lA0 = As + tid * 8;
    bf16* lA1 = As + (tid + 256) * 8;
    bf16* lB0 = Bs + tid * 8;
    bf16* lB1 = Bs + (tid + 256) * 8;

    f32x4 acc[4][4];
    #pragma unroll
    for (int i = 0; i < 4; ++i)
        #pragma unroll
        for (int j = 0; j < 4; ++j) acc[i][j] = f32x4{0.f, 0.f, 0.f, 0.f};

    #pragma unroll 1
    for (int kb = 0; kb < 8; ++kb) {
        const int ko = kb * 32;
        gll16(gA0 + ko, lA0);
        gll16(gA1 + ko, lA1);
        gll16(gB0 + ko, lB0);
        gll16(gB1 + ko, lB1);
        __syncthreads();

        bf16x8 aF[4], bF[4];
        #pragma unroll
        for (int mt = 0; mt < 4; ++mt)
            aF[mt] = *(const bf16x8*)(As + (wr * 64 + mt * 16 + lc) * 32 + quad * 8);
        #pragma unroll
        for (int nt = 0; nt < 4; ++nt)
            bF[nt] = *(const bf16x8*)(Bs + (wc * 64 + nt * 16 + lc) * 32 + quad * 8);
        #pragma unroll
        for (int mt = 0; mt < 4; ++mt)
            #pragma unroll
            for (int nt = 0; nt < 4; ++nt)
                acc[mt][nt] = MFMA16(aF[mt], bF[nt], acc[mt][nt]);
        __syncthreads();
    }

    #pragma unroll
    for (int mt = 0; mt < 4; ++mt) {
        #pragma unroll
        for (int nt = 0; nt < 4; ++nt) {
            const int row = m0 + wr * 64 + mt * 16 + quad * 4;
            const int col = n0 + wc * 64 + nt * 16 + lc;
            if (F32OUT) {
                float b = bo[col];
                #pragma unroll
                for (int rr = 0; rr < 4; ++rr)
                    Cf[(size_t)(row + rr) * ntot + col] = acc[mt][nt][rr] + b;
            } else {
                #pragma unroll
                for (int rr = 0; rr < 4; ++rr)
                    Cb[(size_t)(row + rr) * ntot + col] = (bf16)acc[mt][nt][rr];
            }
        }
    }
}

// Block->tile remap: mi = bid&255 (m-strip), ni = bid>>8.  All ni-variants of an
// A-strip share bid%8 (same XCD) and are ~256 dispatches apart (co-resident) ->
// A-strip read from HBM once, served from that XCD's L2 for the other n-tiles.
__global__ __launch_bounds__(256) void proj_kernel(
    const bf16* __restrict__ qbf, const bf16* __restrict__ kvbf,
    const bf16* __restrict__ Wqg, const bf16* __restrict__ Wkv,
    bf16* __restrict__ QG, bf16* __restrict__ KV)
{
    int bid = blockIdx.x;
    bool sel = bid >= 1024;
    int b = sel ? bid - 1024 : bid;
    int m0 = (b & 255) * 128, n0 = (b >> 8) * 128;
    gemm_core<false>(sel ? kvbf : qbf, sel ? Wkv : Wqg,
                     sel ? KV : QG, nullptr, nullptr, m0, n0, 512);
}

__global__ __launch_bounds__(256) void outproj_kernel(
    const bf16* __restrict__ OG, const bf16* __restrict__ Wo,
    const float* __restrict__ bo, float* __restrict__ out)
{
    int b = blockIdx.x;
    int m0 = (b & 255) * 128, n0 = (b >> 8) * 128;
    gemm_core<true>(OG, Wo, nullptr, out, bo, m0, n0, 256);
}

// ================= attention per (s,h): 256 threads, 4 waves ====================
// Swapped QK^T (S^T = mfma(K, Q)): lane owns ONE q-row (q = lc), 64 k's
// (k = kt*16 + quad*4 + rr).  Softmax fully in-register; P never touches LDS:
// C-layout -> PV B-operand via cvt_pk + permlane32_swap + permlane16_swap.
// LDS: mask[256]f32 @0 | Ks[256][40]bf16 @1024 | Vt[32][264]bf16 @21504
#define A_OFF_MASK 0
#define A_OFF_K    1024
#define A_OFF_VT   21504
#define A_LDS_TOT  (21504 + 32 * 264 * 2)   // 38400 B -> 4 blocks/CU

__global__ __launch_bounds__(256, 4) void attn_kernel(
    const bf16* __restrict__ QG, const bf16* __restrict__ KV,
    const float* __restrict__ biasT, const float* __restrict__ bias_mask,
    const float* __restrict__ b_g, bf16* __restrict__ OG)
{
    __shared__ __align__(16) char smem[A_LDS_TOT];
    float* maskadd = (float*)(smem + A_OFF_MASK);
    bf16*  Ks      = (bf16*)(smem + A_OFF_K);
    bf16*  Vt      = (bf16*)(smem + A_OFF_VT);

    const int tid  = threadIdx.x;
    const int wave = tid >> 6, lane = tid & 63;
    const int quad = lane >> 4, lc = lane & 15;
    const int h = blockIdx.x & 7;        // bid%8 -> one h per XCD: biasT[h] stays L2-hot
    const int s = blockIdx.x >> 3;

    // ---- stage mask, K, V^T ----
    maskadd[tid] = (bias_mask[s * 256 + tid] - 1.0f) * 1e9f;
    {
        const bf16* kvrow = KV + (size_t)(s * 256 + tid) * 512 + h * 32;
        #pragma unroll
        for (int j = 0; j < 4; ++j)
            *(bf16x8*)(Ks + tid * 40 + j * 8) = *(const bf16x8*)(kvrow + j * 8);
        bf16x8 vx[4];
        #pragma unroll
        for (int j = 0; j < 4; ++j) vx[j] = *(const bf16x8*)(kvrow + 256 + j * 8);
        #pragma unroll
        for (int d = 0; d < 32; ++d)
            Vt[d * 264 + tid] = vx[d >> 3][d & 7];
    }
    __syncthreads();

    // gate bias, hoisted (p-independent): b_g[h*32 + nt*16 + quad*4 + rr]
    const f32x4 bg0 = *(const f32x4*)(b_g + h * 32 + quad * 4);
    const f32x4 bg1 = *(const f32x4*)(b_g + h * 32 + 16 + quad * 4);

    #pragma unroll 1
    for (int p = 0; p < 4; ++p) {
        const int q0 = (wave * 4 + p) * 16;

        // B-operand Q^T: lane holds Q[q0+lc][quad*8+j]
        bf16x8 qf = *(const bf16x8*)(QG + (size_t)(s * 256 + q0 + lc) * 512 + h * 32 + quad * 8);

        // S^T[k][q]: lane holds k = kt*16 + quad*4 + rr, q = lc
        f32x4 sc[16];
        #pragma unroll
        for (int kt = 0; kt < 16; ++kt) {
            bf16x8 kf = *(const bf16x8*)(Ks + (kt * 16 + lc) * 40 + quad * 8);
            f32x4 z = {0.f, 0.f, 0.f, 0.f};
            sc[kt] = MFMA16(kf, qf, z);
        }

        // bias now float4-loadable: row q0+lc, cols kt*16+quad*4 .. +3
        const float* bT = biasT + (((size_t)h * 256 + q0 + lc) << 8) + quad * 4;
        float sum = 0.f;
        #pragma unroll
        for (int kt = 0; kt < 16; ++kt) {
            f32x4 bv = *(const f32x4*)(bT + kt * 16);
            f32x4 mv = *(const f32x4*)(maskadd + kt * 16 + quad * 4);
            #pragma unroll
            for (int rr = 0; rr < 4; ++rr) {
                float e = __expf(sc[kt][rr] + bv[rr] + mv[rr]);
                sc[kt][rr] = e;
                sum += e;
            }
        }
        sum += __shfl_xor(sum, 16, 64);
        sum += __shfl_xor(sum, 32, 64);
        const float inv = 1.0f / sum;    // per-lane scalar (one q-row); fold into epilogue

        // PV as O^T = V^T @ P^T.  B-frag for chunk ks needs lane(quad q') to hold
        // P[q=lc][ks*32 + 8q' + j], j=0..7.  Built from sc via 2x2 lane-group
        // transposes: {r0,r2}=pl16swap(pl32swap(c0,c2)), {r1,r3}=pl16swap(pl32swap(c1,c3)).
        f32x4 o0 = {0.f, 0.f, 0.f, 0.f}, o1 = {0.f, 0.f, 0.f, 0.f};
        #pragma unroll
        for (int ks = 0; ks < 8; ++ks) {
            u32 c0 = pk2(sc[2 * ks][0],     sc[2 * ks][1]);
            u32 c1 = pk2(sc[2 * ks][2],     sc[2 * ks][3]);
            u32 c2 = pk2(sc[2 * ks + 1][0], sc[2 * ks + 1][1]);
            u32 c3 = pk2(sc[2 * ks + 1][2], sc[2 * ks + 1][3]);
            u32x2 s02 = __builtin_amdgcn_permlane32_swap(c0, c2, false, false);
            u32x2 s13 = __builtin_amdgcn_permlane32_swap(c1, c3, false, false);
            u32x2 e02 = __builtin_amdgcn_permlane16_swap(s02.x, s02.y, false, false);
            u32x2 e13 = __builtin_amdgcn_permlane16_swap(s13.x, s13.y, false, false);
            u32x4 pw = {e02.x, e13.x, e02.y, e13.y};
            bf16x8 pf = __builtin_bit_cast(bf16x8, pw);
            bf16x8 v0 = *(const bf16x8*)(Vt + lc * 264 + ks * 32 + quad * 8);
            bf16x8 v1 = *(const bf16x8*)(Vt + (16 + lc) * 264 + ks * 32 + quad * 8);
            o0 = MFMA16(v0, pf, o0);
            o1 = MFMA16(v1, pf, o1);
        }

        // epilogue: lane holds O^T[d = nt*16 + quad*4 + rr][q = lc]
        const bf16* gp = QG + (size_t)(s * 256 + q0 + lc) * 512 + 256 + h * 32 + quad * 4;
        bf16*       op = OG + (size_t)(s * 256 + q0 + lc) * 256 + h * 32 + quad * 4;
        #pragma unroll
        for (int nt = 0; nt < 2; ++nt) {
            f32x4 ov = nt ? o1 : o0;
            f32x4 bg = nt ? bg1 : bg0;
            bf16x4 gv = *(const bf16x4*)(gp + nt * 16);
            bf16x4 ob;
            #pragma unroll
            for (int rr = 0; rr < 4; ++rr) {
                float g = 1.0f / (1.0f + __expf(-((float)gv[rr] + bg[rr])));
                ob[rr] = (bf16)(ov[rr] * inv * g);
            }
            *(bf16x4*)(op + nt * 16) = ob;
        }
    }
}

// ================= launch =================
extern "C" void kernel_launch(void* const* d_in, const int* in_sizes, int n_in,
                              void* d_out, int out_size, void* d_ws, size_t ws_size,
                              hipStream_t stream)
{
    (void)in_sizes; (void)n_in; (void)out_size; (void)ws_size;
    const float* q    = (const float*)d_in[0];
    const float* kv   = (const float*)d_in[1];
    const float* bias = (const float*)d_in[2];
    const float* mask = (const float*)d_in[3];
    const float* w_q  = (const float*)d_in[4];
    const float* w_k  = (const float*)d_in[5];
    const float* w_v  = (const float*)d_in[6];
    const float* w_g  = (const float*)d_in[7];
    const float* b_g  = (const float*)d_in[8];
    const float* w_o  = (const float*)d_in[9];
    const float* b_o  = (const float*)d_in[10];
    float* out = (float*)d_out;

    char* ws = (char*)d_ws;
    bf16*  qbf   = (bf16*)(ws + 0);           // 16.78 MB  (aliased: OG after proj)
    bf16*  kvbf  = (bf16*)(ws + 16777216);    // 16.78 MB
    bf16*  QG    = (bf16*)(ws + 33554432);    // 33.55 MB  [32768][512] = [Q*norm | G]
    bf16*  KV    = (bf16*)(ws + 67108864);    // 33.55 MB  [32768][512] = [K | V]
    float* biasT = (float*)(ws + 100663296);  //  2.10 MB  [h][q][k]
    bf16*  Wqg   = (bf16*)(ws + 102760448);   //  0.26 MB
    bf16*  Wkv   = (bf16*)(ws + 103022592);   //  0.26 MB
    bf16*  Wo    = (bf16*)(ws + 103284736);   //  0.13 MB
    bf16*  OG    = qbf;                       // alias: qbf dead after proj_kernel

    prep_kernel<<<1024, 256, 0, stream>>>(q, kv, bias, w_q, w_k, w_v, w_g, w_o,
                                          qbf, kvbf, biasT, Wqg, Wkv, Wo);
    proj_kernel<<<2048, 256, 0, stream>>>(qbf, kvbf, Wqg, Wkv, QG, KV);
    attn_kernel<<<1024, 256, 0, stream>>>(QG, KV, biasT, mask, b_g, OG);
    outproj_kernel<<<512, 256, 0, stream>>>(OG, Wo, b_o, out);
}

// Round 2
// 263.510 us; speedup vs baseline: 1.3332x; 1.3332x over previous
//
#include <hip/hip_runtime.h>

typedef __bf16 bf16;
typedef __bf16 bf16x8 __attribute__((ext_vector_type(8)));
typedef __bf16 bf16x4 __attribute__((ext_vector_type(4)));
typedef float  f32x4  __attribute__((ext_vector_type(4)));
typedef unsigned int u32;
typedef unsigned int u32x2 __attribute__((ext_vector_type(2)));
typedef unsigned int u32x4 __attribute__((ext_vector_type(4)));
typedef unsigned short u16;

#define MFMA16(a, b, c) __builtin_amdgcn_mfma_f32_16x16x32_bf16((a), (b), (c), 0, 0, 0)

// B=1, S=128, R=256, C=256, H=8, Ca=32.  M = S*R = 32768, K = 256.

// ---- async global->LDS, 16 B per lane (guide §5: width=16) ----
typedef __attribute__((address_space(3))) u32 lds_u32;
typedef const __attribute__((address_space(1))) u32 glob_u32;
__device__ __forceinline__ void gll16(const void* g, void* l) {
    __builtin_amdgcn_global_load_lds((glob_u32*)g, (lds_u32*)l, 16, 0, 0);
}

// pack two f32 -> one u32 of 2 bf16 (lo, hi); compiler emits v_cvt_pk_bf16_f32
__device__ __forceinline__ u32 pk2(float lo, float hi) {
    u16 a = __builtin_bit_cast(u16, (bf16)lo);
    u16 b = __builtin_bit_cast(u16, (bf16)hi);
    return ((u32)b << 16) | (u32)a;
}

// ================= prep: bf16 convert + weight/bias transposes =================
__global__ __launch_bounds__(256) void prep_kernel(
    const float* __restrict__ q, const float* __restrict__ kv,
    const float* __restrict__ bias,
    const float* __restrict__ w_q, const float* __restrict__ w_k,
    const float* __restrict__ w_v, const float* __restrict__ w_g,
    const float* __restrict__ w_o,
    bf16* __restrict__ qbf, bf16* __restrict__ kvbf, float* __restrict__ biasT,
    bf16* __restrict__ Wqg, bf16* __restrict__ Wkv, bf16* __restrict__ Wo)
{
    const float norm = 0.17677669529663687f;  // 1/sqrt(32) baked into Wq
    const int gid = blockIdx.x * 256 + threadIdx.x;
    const int gsz = gridDim.x * 256;

    // q/kv -> bf16, 8 elems per unit (vectorized)
    for (int u = gid; u < 2097152; u += gsz) {
        const float* src; bf16* dst;
        if (u < 1048576) { src = q + (size_t)u * 8;            dst = qbf  + (size_t)u * 8; }
        else             { src = kv + (size_t)(u - 1048576)*8; dst = kvbf + (size_t)(u - 1048576)*8; }
        float4 x0 = *(const float4*)(src);
        float4 x1 = *(const float4*)(src + 4);
        bf16x8 t;
        t[0]=(bf16)x0.x; t[1]=(bf16)x0.y; t[2]=(bf16)x0.z; t[3]=(bf16)x0.w;
        t[4]=(bf16)x1.x; t[5]=(bf16)x1.y; t[6]=(bf16)x1.z; t[7]=(bf16)x1.w;
        *(bf16x8*)dst = t;
    }
    // biasT[h][q][k] <- bias[q][k][h]  (coalesced writes)
    for (int u = gid; u < 524288; u += gsz) {
        int h = u >> 16, qq = (u >> 8) & 255, kk = u & 255;
        biasT[u] = bias[(((qq << 8) + kk) << 3) + h];
    }
    // Wqg[n][k]: n<256 -> w_q[k][n]*norm ; else w_g[k][n-256]
    for (int u = gid; u < 131072; u += gsz) {
        int n = u >> 8, k = u & 255;
        float v = (n < 256) ? w_q[k * 256 + n] * norm : w_g[k * 256 + (n - 256)];
        Wqg[u] = (bf16)v;
    }
    // Wkv[n][k]: n<256 -> w_k[k][n] ; else w_v[k][n-256]
    for (int u = gid; u < 131072; u += gsz) {
        int n = u >> 8, k = u & 255;
        float v = (n < 256) ? w_k[k * 256 + n] : w_v[k * 256 + (n - 256)];
        Wkv[u] = (bf16)v;
    }
    // Wo[n][k] = w_o[k][n]   ([H*Ca][C] -> [C][H*Ca])
    for (int u = gid; u < 65536; u += gsz) {
        int n = u >> 8, k = u & 255;
        Wo[u] = (bf16)w_o[k * 256 + n];
    }
}

// ================= tiled GEMM core: C[M][ntot] = A[M][256] @ Bw[ntot][256]^T ===
// 128x128 tile, 256 threads (4 waves, each 64x64), BK=32, global_load_lds staging.
template<bool F32OUT>
__device__ __forceinline__ void gemm_core(
    const bf16* __restrict__ A, const bf16* __restrict__ Bw,
    bf16* __restrict__ Cb, float* __restrict__ Cf, const float* __restrict__ bo,
    int m0, int n0, int ntot)
{
    __shared__ __align__(16) bf16 As[128 * 32];
    __shared__ __align__(16) bf16 Bs[128 * 32];

    const int tid  = threadIdx.x;
    const int lane = tid & 63, wave = tid >> 6;
    const int quad = lane >> 4, lc = lane & 15;
    const int wr = wave >> 1, wc = wave & 1;

    const int r0 = tid >> 2, p0 = tid & 3;
    const bf16* gA0 = A  + (size_t)(m0 + r0) * 256 + p0 * 8;
    const bf16* gA1 = A  + (size_t)(m0 + 64 + r0) * 256 + p0 * 8;
    const bf16* gB0 = Bw + (size_t)(n0 + r0) * 256 + p0 * 8;
    const bf16* gB1 = Bw + (size_t)(n0 + 64 + r0) * 256 + p0 * 8;
    bf16* lA0 = As + tid * 8;
    bf16* lA1 = As + (tid + 256) * 8;
    bf16* lB0 = Bs + tid * 8;
    bf16* lB1 = Bs + (tid + 256) * 8;

    f32x4 acc[4][4];
    #pragma unroll
    for (int i = 0; i < 4; ++i)
        #pragma unroll
        for (int j = 0; j < 4; ++j) acc[i][j] = f32x4{0.f, 0.f, 0.f, 0.f};

    #pragma unroll 1
    for (int kb = 0; kb < 8; ++kb) {
        const int ko = kb * 32;
        gll16(gA0 + ko, lA0);
        gll16(gA1 + ko, lA1);
        gll16(gB0 + ko, lB0);
        gll16(gB1 + ko, lB1);
        __syncthreads();

        bf16x8 aF[4], bF[4];
        #pragma unroll
        for (int mt = 0; mt < 4; ++mt)
            aF[mt] = *(const bf16x8*)(As + (wr * 64 + mt * 16 + lc) * 32 + quad * 8);
        #pragma unroll
        for (int nt = 0; nt < 4; ++nt)
            bF[nt] = *(const bf16x8*)(Bs + (wc * 64 + nt * 16 + lc) * 32 + quad * 8);
        #pragma unroll
        for (int mt = 0; mt < 4; ++mt)
            #pragma unroll
            for (int nt = 0; nt < 4; ++nt)
                acc[mt][nt] = MFMA16(aF[mt], bF[nt], acc[mt][nt]);
        __syncthreads();
    }

    #pragma unroll
    for (int mt = 0; mt < 4; ++mt) {
        #pragma unroll
        for (int nt = 0; nt < 4; ++nt) {
            const int row = m0 + wr * 64 + mt * 16 + quad * 4;
            const int col = n0 + wc * 64 + nt * 16 + lc;
            if (F32OUT) {
                float b = bo[col];
                #pragma unroll
                for (int rr = 0; rr < 4; ++rr)
                    Cf[(size_t)(row + rr) * ntot + col] = acc[mt][nt][rr] + b;
            } else {
                #pragma unroll
                for (int rr = 0; rr < 4; ++rr)
                    Cb[(size_t)(row + rr) * ntot + col] = (bf16)acc[mt][nt][rr];
            }
        }
    }
}

// Block->tile remap: mi = bid&255 (m-strip), ni = bid>>8.  All ni-variants of an
// A-strip share bid%8 (same XCD) and are ~256 dispatches apart (co-resident) ->
// A-strip read from HBM once, served from that XCD's L2 for the other n-tiles.
__global__ __launch_bounds__(256) void proj_kernel(
    const bf16* __restrict__ qbf, const bf16* __restrict__ kvbf,
    const bf16* __restrict__ Wqg, const bf16* __restrict__ Wkv,
    bf16* __restrict__ QG, bf16* __restrict__ KV)
{
    int bid = blockIdx.x;
    bool sel = bid >= 1024;
    int b = sel ? bid - 1024 : bid;
    int m0 = (b & 255) * 128, n0 = (b >> 8) * 128;
    gemm_core<false>(sel ? kvbf : qbf, sel ? Wkv : Wqg,
                     sel ? KV : QG, nullptr, nullptr, m0, n0, 512);
}

__global__ __launch_bounds__(256) void outproj_kernel(
    const bf16* __restrict__ OG, const bf16* __restrict__ Wo,
    const float* __restrict__ bo, float* __restrict__ out)
{
    int b = blockIdx.x;
    int m0 = (b & 255) * 128, n0 = (b >> 8) * 128;
    gemm_core<true>(OG, Wo, nullptr, out, bo, m0, n0, 256);
}

// ================= attention per (s,h): 256 threads, 4 waves ====================
// Swapped QK^T (S^T = mfma(K, Q)): lane owns ONE q-row (q = lc), 64 k's
// (k = kt*16 + quad*4 + rr).  Softmax fully in-register; P never touches LDS:
// C-layout -> PV B-operand via cvt_pk + permlane32_swap + permlane16_swap.
// P is packed to bf16 words EARLY (in the exp pass) so only 32 u32 stay live,
// not 64 f32 -> no VGPR spill.  NOTE: no forced min-occupancy in launch_bounds
// (round-1: __launch_bounds__(256,4) made the allocator spill sc[] to scratch:
// VGPR 120->64, WRITE_SIZE 16.6->184 MB, 2.7x slower).
// LDS: mask[256]f32 @0 | Ks[256][40]bf16 @1024 | Vt[32][264]bf16 @21504
#define A_OFF_MASK 0
#define A_OFF_K    1024
#define A_OFF_VT   21504
#define A_LDS_TOT  (21504 + 32 * 264 * 2)   // 38400 B -> 4 blocks/CU (LDS limit)

__global__ __launch_bounds__(256) void attn_kernel(
    const bf16* __restrict__ QG, const bf16* __restrict__ KV,
    const float* __restrict__ biasT, const float* __restrict__ bias_mask,
    const float* __restrict__ b_g, bf16* __restrict__ OG)
{
    __shared__ __align__(16) char smem[A_LDS_TOT];
    float* maskadd = (float*)(smem + A_OFF_MASK);
    bf16*  Ks      = (bf16*)(smem + A_OFF_K);
    bf16*  Vt      = (bf16*)(smem + A_OFF_VT);

    const int tid  = threadIdx.x;
    const int wave = tid >> 6, lane = tid & 63;
    const int quad = lane >> 4, lc = lane & 15;
    const int h = blockIdx.x & 7;        // bid%8 -> one h per XCD: biasT[h] stays L2-hot
    const int s = blockIdx.x >> 3;

    // ---- stage mask, K, V^T ----
    maskadd[tid] = (bias_mask[s * 256 + tid] - 1.0f) * 1e9f;
    {
        const bf16* kvrow = KV + (size_t)(s * 256 + tid) * 512 + h * 32;
        #pragma unroll
        for (int j = 0; j < 4; ++j)
            *(bf16x8*)(Ks + tid * 40 + j * 8) = *(const bf16x8*)(kvrow + j * 8);
        bf16x8 vx[4];
        #pragma unroll
        for (int j = 0; j < 4; ++j) vx[j] = *(const bf16x8*)(kvrow + 256 + j * 8);
        #pragma unroll
        for (int d = 0; d < 32; ++d)
            Vt[d * 264 + tid] = vx[d >> 3][d & 7];
    }
    __syncthreads();

    // gate bias, hoisted (p-independent): b_g[h*32 + nt*16 + quad*4 + rr]
    const f32x4 bg0 = *(const f32x4*)(b_g + h * 32 + quad * 4);
    const f32x4 bg1 = *(const f32x4*)(b_g + h * 32 + 16 + quad * 4);

    #pragma unroll 1
    for (int p = 0; p < 4; ++p) {
        const int q0 = (wave * 4 + p) * 16;

        // B-operand Q^T: lane holds Q[q0+lc][quad*8+j]
        bf16x8 qf = *(const bf16x8*)(QG + (size_t)(s * 256 + q0 + lc) * 512 + h * 32 + quad * 8);

        // S^T[k][q]: lane holds k = kt*16 + quad*4 + rr, q = lc
        f32x4 sc[16];
        #pragma unroll
        for (int kt = 0; kt < 16; ++kt) {
            bf16x8 kf = *(const bf16x8*)(Ks + (kt * 16 + lc) * 40 + quad * 8);
            f32x4 z = {0.f, 0.f, 0.f, 0.f};
            sc[kt] = MFMA16(kf, qf, z);
        }

        // bias float4-loadable: row q0+lc, cols kt*16+quad*4 .. +3.
        // Pack P to bf16 words immediately (un-normalized; inv folded into epilogue).
        const float* bT = biasT + (((size_t)h * 256 + q0 + lc) << 8) + quad * 4;
        u32x2 cw[16];
        float sum = 0.f;
        #pragma unroll
        for (int kt = 0; kt < 16; ++kt) {
            f32x4 bv = *(const f32x4*)(bT + kt * 16);
            f32x4 mv = *(const f32x4*)(maskadd + kt * 16 + quad * 4);
            float e0 = __expf(sc[kt][0] + bv[0] + mv[0]);
            float e1 = __expf(sc[kt][1] + bv[1] + mv[1]);
            float e2 = __expf(sc[kt][2] + bv[2] + mv[2]);
            float e3 = __expf(sc[kt][3] + bv[3] + mv[3]);
            sum += (e0 + e1) + (e2 + e3);
            cw[kt] = u32x2{pk2(e0, e1), pk2(e2, e3)};
        }
        sum += __shfl_xor(sum, 16, 64);
        sum += __shfl_xor(sum, 32, 64);
        const float inv = 1.0f / sum;    // per-lane scalar (one q-row)

        // PV as O^T = V^T @ P^T.  B-frag for chunk ks needs lane(quad q') to hold
        // P[q=lc][ks*32 + 8q' + j], j=0..7.  Built via 2x2 lane-group transposes:
        // {r0,r2}=pl16swap(pl32swap(c0,c2)), {r1,r3}=pl16swap(pl32swap(c1,c3)).
        f32x4 o0 = {0.f, 0.f, 0.f, 0.f}, o1 = {0.f, 0.f, 0.f, 0.f};
        #pragma unroll
        for (int ks = 0; ks < 8; ++ks) {
            u32 c0 = cw[2 * ks].x,     c1 = cw[2 * ks].y;
            u32 c2 = cw[2 * ks + 1].x, c3 = cw[2 * ks + 1].y;
            u32x2 s02 = __builtin_amdgcn_permlane32_swap(c0, c2, false, false);
            u32x2 s13 = __builtin_amdgcn_permlane32_swap(c1, c3, false, false);
            u32x2 e02 = __builtin_amdgcn_permlane16_swap(s02.x, s02.y, false, false);
            u32x2 e13 = __builtin_amdgcn_permlane16_swap(s13.x, s13.y, false, false);
            u32x4 pw = {e02.x, e13.x, e02.y, e13.y};
            bf16x8 pf = __builtin_bit_cast(bf16x8, pw);
            bf16x8 v0 = *(const bf16x8*)(Vt + lc * 264 + ks * 32 + quad * 8);
            bf16x8 v1 = *(const bf16x8*)(Vt + (16 + lc) * 264 + ks * 32 + quad * 8);
            o0 = MFMA16(v0, pf, o0);
            o1 = MFMA16(v1, pf, o1);
        }

        // epilogue: lane holds O^T[d = nt*16 + quad*4 + rr][q = lc]
        const bf16* gp = QG + (size_t)(s * 256 + q0 + lc) * 512 + 256 + h * 32 + quad * 4;
        bf16*       op = OG + (size_t)(s * 256 + q0 + lc) * 256 + h * 32 + quad * 4;
        #pragma unroll
        for (int nt = 0; nt < 2; ++nt) {
            f32x4 ov = nt ? o1 : o0;
            f32x4 bg = nt ? bg1 : bg0;
            bf16x4 gv = *(const bf16x4*)(gp + nt * 16);
            bf16x4 ob;
            #pragma unroll
            for (int rr = 0; rr < 4; ++rr) {
                float g = 1.0f / (1.0f + __expf(-((float)gv[rr] + bg[rr])));
                ob[rr] = (bf16)(ov[rr] * inv * g);
            }
            *(bf16x4*)(op + nt * 16) = ob;
        }
    }
}

// ================= launch =================
extern "C" void kernel_launch(void* const* d_in, const int* in_sizes, int n_in,
                              void* d_out, int out_size, void* d_ws, size_t ws_size,
                              hipStream_t stream)
{
    (void)in_sizes; (void)n_in; (void)out_size; (void)ws_size;
    const float* q    = (const float*)d_in[0];
    const float* kv   = (const float*)d_in[1];
    const float* bias = (const float*)d_in[2];
    const float* mask = (const float*)d_in[3];
    const float* w_q  = (const float*)d_in[4];
    const float* w_k  = (const float*)d_in[5];
    const float* w_v  = (const float*)d_in[6];
    const float* w_g  = (const float*)d_in[7];
    const float* b_g  = (const float*)d_in[8];
    const float* w_o  = (const float*)d_in[9];
    const float* b_o  = (const float*)d_in[10];
    float* out = (float*)d_out;

    char* ws = (char*)d_ws;
    bf16*  qbf   = (bf16*)(ws + 0);           // 16.78 MB  (aliased: OG after proj)
    bf16*  kvbf  = (bf16*)(ws + 16777216);    // 16.78 MB
    bf16*  QG    = (bf16*)(ws + 33554432);    // 33.55 MB  [32768][512] = [Q*norm | G]
    bf16*  KV    = (bf16*)(ws + 67108864);    // 33.55 MB  [32768][512] = [K | V]
    float* biasT = (float*)(ws + 100663296);  //  2.10 MB  [h][q][k]
    bf16*  Wqg   = (bf16*)(ws + 102760448);   //  0.26 MB
    bf16*  Wkv   = (bf16*)(ws + 103022592);   //  0.26 MB
    bf16*  Wo    = (bf16*)(ws + 103284736);   //  0.13 MB
    bf16*  OG    = qbf;                       // alias: qbf dead after proj_kernel

    prep_kernel<<<1024, 256, 0, stream>>>(q, kv, bias, w_q, w_k, w_v, w_g, w_o,
                                          qbf, kvbf, biasT, Wqg, Wkv, Wo);
    proj_kernel<<<2048, 256, 0, stream>>>(qbf, kvbf, Wqg, Wkv, QG, KV);
    attn_kernel<<<1024, 256, 0, stream>>>(QG, KV, biasT, mask, b_g, OG);
    outproj_kernel<<<512, 256, 0, stream>>>(OG, Wo, b_o, out);
}

// Round 3
// 214.112 us; speedup vs baseline: 1.6408x; 1.2307x over previous
//
#include <hip/hip_runtime.h>

typedef __bf16 bf16;
typedef __bf16 bf16x8 __attribute__((ext_vector_type(8)));
typedef __bf16 bf16x4 __attribute__((ext_vector_type(4)));
typedef float  f32x4  __attribute__((ext_vector_type(4)));
typedef unsigned int u32;
typedef unsigned int u32x2 __attribute__((ext_vector_type(2)));
typedef unsigned int u32x4 __attribute__((ext_vector_type(4)));
typedef unsigned short u16;

#define MFMA16(a, b, c) __builtin_amdgcn_mfma_f32_16x16x32_bf16((a), (b), (c), 0, 0, 0)
#define L2E 1.4426950408889634f

// B=1, S=128, R=256, C=256, H=8, Ca=32.  M = S*R = 32768, K = 256.

// ---- async global->LDS, 16 B per lane (guide §5: width=16) ----
typedef __attribute__((address_space(3))) u32 lds_u32;
typedef const __attribute__((address_space(1))) u32 glob_u32;
__device__ __forceinline__ void gll16(const void* g, void* l) {
    __builtin_amdgcn_global_load_lds((glob_u32*)g, (lds_u32*)l, 16, 0, 0);
}

// pack two f32 -> one u32 of 2 bf16 (lo, hi); compiler emits v_cvt_pk_bf16_f32
__device__ __forceinline__ u32 pk2(float lo, float hi) {
    u16 a = __builtin_bit_cast(u16, (bf16)lo);
    u16 b = __builtin_bit_cast(u16, (bf16)hi);
    return ((u32)b << 16) | (u32)a;
}

// 2^x via v_exp_f32 (log2e pre-folded into Q-scale/bias/mask at prep)
__device__ __forceinline__ float fexp2(float x) {
#if __has_builtin(__builtin_amdgcn_exp2f)
    return __builtin_amdgcn_exp2f(x);
#else
    return exp2f(x);
#endif
}

// ================= prep: bf16 convert + weight/bias transposes =================
__global__ __launch_bounds__(256) void prep_kernel(
    const float* __restrict__ q, const float* __restrict__ kv,
    const float* __restrict__ bias,
    const float* __restrict__ w_q, const float* __restrict__ w_k,
    const float* __restrict__ w_v, const float* __restrict__ w_g,
    const float* __restrict__ w_o,
    bf16* __restrict__ qbf, bf16* __restrict__ kvbf, float* __restrict__ biasT,
    bf16* __restrict__ Wqg, bf16* __restrict__ Wkv, bf16* __restrict__ Wo)
{
    // 1/sqrt(32) * log2(e): softmax computed in base-2 (exp2)
    const float norm = 0.17677669529663687f * L2E;
    const int gid = blockIdx.x * 256 + threadIdx.x;
    const int gsz = gridDim.x * 256;

    // q/kv -> bf16, 8 elems per unit (vectorized)
    for (int u = gid; u < 2097152; u += gsz) {
        const float* src; bf16* dst;
        if (u < 1048576) { src = q + (size_t)u * 8;            dst = qbf  + (size_t)u * 8; }
        else             { src = kv + (size_t)(u - 1048576)*8; dst = kvbf + (size_t)(u - 1048576)*8; }
        float4 x0 = *(const float4*)(src);
        float4 x1 = *(const float4*)(src + 4);
        bf16x8 t;
        t[0]=(bf16)x0.x; t[1]=(bf16)x0.y; t[2]=(bf16)x0.z; t[3]=(bf16)x0.w;
        t[4]=(bf16)x1.x; t[5]=(bf16)x1.y; t[6]=(bf16)x1.z; t[7]=(bf16)x1.w;
        *(bf16x8*)dst = t;
    }
    // biasT[h][q][k] <- bias[q][k][h] * log2e  (coalesced writes)
    for (int u = gid; u < 524288; u += gsz) {
        int h = u >> 16, qq = (u >> 8) & 255, kk = u & 255;
        biasT[u] = bias[(((qq << 8) + kk) << 3) + h] * L2E;
    }
    // Wqg[n][k]: n<256 -> w_q[k][n]*norm ; else w_g[k][n-256]
    for (int u = gid; u < 131072; u += gsz) {
        int n = u >> 8, k = u & 255;
        float v = (n < 256) ? w_q[k * 256 + n] * norm : w_g[k * 256 + (n - 256)];
        Wqg[u] = (bf16)v;
    }
    // Wkv[n][k]: n<256 -> w_k[k][n] ; else w_v[k][n-256]
    for (int u = gid; u < 131072; u += gsz) {
        int n = u >> 8, k = u & 255;
        float v = (n < 256) ? w_k[k * 256 + n] : w_v[k * 256 + (n - 256)];
        Wkv[u] = (bf16)v;
    }
    // Wo[n][k] = w_o[k][n]   ([H*Ca][C] -> [C][H*Ca])
    for (int u = gid; u < 65536; u += gsz) {
        int n = u >> 8, k = u & 255;
        Wo[u] = (bf16)w_o[k * 256 + n];
    }
}

// ================= tiled GEMM core: C[M][ntot] = A[M][256] @ Bw[ntot][256]^T ===
// 128x128 tile, 256 threads (4 waves, each 64x64), BK=32, global_load_lds staging.
template<bool F32OUT>
__device__ __forceinline__ void gemm_core(
    const bf16* __restrict__ A, const bf16* __restrict__ Bw,
    bf16* __restrict__ Cb, float* __restrict__ Cf, const float* __restrict__ bo,
    int m0, int n0, int ntot)
{
    __shared__ __align__(16) bf16 As[128 * 32];
    __shared__ __align__(16) bf16 Bs[128 * 32];

    const int tid  = threadIdx.x;
    const int lane = tid & 63, wave = tid >> 6;
    const int quad = lane >> 4, lc = lane & 15;
    const int wr = wave >> 1, wc = wave & 1;

    const int r0 = tid >> 2, p0 = tid & 3;
    const bf16* gA0 = A  + (size_t)(m0 + r0) * 256 + p0 * 8;
    const bf16* gA1 = A  + (size_t)(m0 + 64 + r0) * 256 + p0 * 8;
    const bf16* gB0 = Bw + (size_t)(n0 + r0) * 256 + p0 * 8;
    const bf16* gB1 = Bw + (size_t)(n0 + 64 + r0) * 256 + p0 * 8;
    bf16* lA0 = As + tid * 8;
    bf16* lA1 = As + (tid + 256) * 8;
    bf16* lB0 = Bs + tid * 8;
    bf16* lB1 = Bs + (tid + 256) * 8;

    f32x4 acc[4][4];
    #pragma unroll
    for (int i = 0; i < 4; ++i)
        #pragma unroll
        for (int j = 0; j < 4; ++j) acc[i][j] = f32x4{0.f, 0.f, 0.f, 0.f};

    #pragma unroll 1
    for (int kb = 0; kb < 8; ++kb) {
        const int ko = kb * 32;
        gll16(gA0 + ko, lA0);
        gll16(gA1 + ko, lA1);
        gll16(gB0 + ko, lB0);
        gll16(gB1 + ko, lB1);
        __syncthreads();

        bf16x8 aF[4], bF[4];
        #pragma unroll
        for (int mt = 0; mt < 4; ++mt)
            aF[mt] = *(const bf16x8*)(As + (wr * 64 + mt * 16 + lc) * 32 + quad * 8);
        #pragma unroll
        for (int nt = 0; nt < 4; ++nt)
            bF[nt] = *(const bf16x8*)(Bs + (wc * 64 + nt * 16 + lc) * 32 + quad * 8);
        #pragma unroll
        for (int mt = 0; mt < 4; ++mt)
            #pragma unroll
            for (int nt = 0; nt < 4; ++nt)
                acc[mt][nt] = MFMA16(aF[mt], bF[nt], acc[mt][nt]);
        __syncthreads();
    }

    #pragma unroll
    for (int mt = 0; mt < 4; ++mt) {
        #pragma unroll
        for (int nt = 0; nt < 4; ++nt) {
            const int row = m0 + wr * 64 + mt * 16 + quad * 4;
            const int col = n0 + wc * 64 + nt * 16 + lc;
            if (F32OUT) {
                float b = bo[col];
                #pragma unroll
                for (int rr = 0; rr < 4; ++rr)
                    Cf[(size_t)(row + rr) * ntot + col] = acc[mt][nt][rr] + b;
            } else {
                #pragma unroll
                for (int rr = 0; rr < 4; ++rr)
                    Cb[(size_t)(row + rr) * ntot + col] = (bf16)acc[mt][nt][rr];
            }
        }
    }
}

// Block->tile remap: mi = bid&255 (m-strip), ni = bid>>8.  All ni-variants of an
// A-strip share bid%8 (same XCD) and are ~256 dispatches apart (co-resident) ->
// A-strip read from HBM once, served from that XCD's L2 for the other n-tiles.
__global__ __launch_bounds__(256) void proj_kernel(
    const bf16* __restrict__ qbf, const bf16* __restrict__ kvbf,
    const bf16* __restrict__ Wqg, const bf16* __restrict__ Wkv,
    bf16* __restrict__ QG, bf16* __restrict__ KV)
{
    int bid = blockIdx.x;
    bool sel = bid >= 1024;
    int b = sel ? bid - 1024 : bid;
    int m0 = (b & 255) * 128, n0 = (b >> 8) * 128;
    gemm_core<false>(sel ? kvbf : qbf, sel ? Wkv : Wqg,
                     sel ? KV : QG, nullptr, nullptr, m0, n0, 512);
}

__global__ __launch_bounds__(256) void outproj_kernel(
    const bf16* __restrict__ OG, const bf16* __restrict__ Wo,
    const float* __restrict__ bo, float* __restrict__ out)
{
    int b = blockIdx.x;
    int m0 = (b & 255) * 128, n0 = (b >> 8) * 128;
    gemm_core<true>(OG, Wo, nullptr, out, bo, m0, n0, 256);
}

// ================= attention per (s,h): 256 threads, 4 waves ====================
// Swapped QK^T (S^T = mfma(K, Q)): lane owns ONE q-row (q = lc), 64 k's.
// Softmax in-register (base-2, log2e pre-folded); P -> PV B-operand via
// cvt_pk + permlane32_swap + permlane16_swap; never touches LDS.
// Round-2 lesson: holding sc[16] (64 f32) through the whole exp pass -> VGPR 160
// -> occupancy cliff (8 waves/CU, m69 quantization).  Fix: QK^T in two 8-kt
// halves (MFMA 8 -> exp/pack 8), sched_barrier between, target VGPR <= 128.
// Block map: h = bid>>7, s = bid&127 -> XCD(bid%8) = s%8: all 8 h's of a row-s
// share one XCD's L2 (QG/KV lines fetched once); biasT 2 MB/XCD fits 4 MB L2.
// LDS: mask[256]f32 @0 | Ks[256][40]bf16 @1024 | Vt[32][264]bf16 @21504
#define A_OFF_MASK 0
#define A_OFF_K    1024
#define A_OFF_VT   21504
#define A_LDS_TOT  (21504 + 32 * 264 * 2)   // 38400 B -> 4 blocks/CU (LDS limit)

__global__ __launch_bounds__(256) void attn_kernel(
    const bf16* __restrict__ QG, const bf16* __restrict__ KV,
    const float* __restrict__ biasT, const float* __restrict__ bias_mask,
    const float* __restrict__ b_g, bf16* __restrict__ OG)
{
    __shared__ __align__(16) char smem[A_LDS_TOT];
    float* maskadd = (float*)(smem + A_OFF_MASK);
    bf16*  Ks      = (bf16*)(smem + A_OFF_K);
    bf16*  Vt      = (bf16*)(smem + A_OFF_VT);

    const int tid  = threadIdx.x;
    const int wave = tid >> 6, lane = tid & 63;
    const int quad = lane >> 4, lc = lane & 15;
    const int h = blockIdx.x >> 7;       // all h of same s -> same XCD (bid%8 = s%8)
    const int s = blockIdx.x & 127;

    // ---- stage mask, K, V^T ----
    maskadd[tid] = (bias_mask[s * 256 + tid] - 1.0f) * (1e9f * L2E);
    {
        const bf16* kvrow = KV + (size_t)(s * 256 + tid) * 512 + h * 32;
        #pragma unroll
        for (int j = 0; j < 4; ++j)
            *(bf16x8*)(Ks + tid * 40 + j * 8) = *(const bf16x8*)(kvrow + j * 8);
        bf16x8 vx[4];
        #pragma unroll
        for (int j = 0; j < 4; ++j) vx[j] = *(const bf16x8*)(kvrow + 256 + j * 8);
        #pragma unroll
        for (int d = 0; d < 32; ++d)
            Vt[d * 264 + tid] = vx[d >> 3][d & 7];
    }
    __syncthreads();

    #pragma unroll 1
    for (int p = 0; p < 4; ++p) {
        const int q0 = (wave * 4 + p) * 16;

        // B-operand Q^T: lane holds Q[q0+lc][quad*8+j]
        bf16x8 qf = *(const bf16x8*)(QG + (size_t)(s * 256 + q0 + lc) * 512 + h * 32 + quad * 8);

        // S^T[k][q] in two 8-kt halves to halve sc live range (VGPR <= 128).
        const float* bT = biasT + (((size_t)h * 256 + q0 + lc) << 8) + quad * 4;
        u32x2 cw[16];
        float sum = 0.f;
        #pragma unroll
        for (int half = 0; half < 2; ++half) {
            f32x4 sc[8];
            #pragma unroll
            for (int k8 = 0; k8 < 8; ++k8) {
                const int kt = half * 8 + k8;
                bf16x8 kf = *(const bf16x8*)(Ks + (kt * 16 + lc) * 40 + quad * 8);
                f32x4 z = {0.f, 0.f, 0.f, 0.f};
                sc[k8] = MFMA16(kf, qf, z);
            }
            #pragma unroll
            for (int k8 = 0; k8 < 8; ++k8) {
                const int kt = half * 8 + k8;
                f32x4 bv = *(const f32x4*)(bT + kt * 16);
                f32x4 mv = *(const f32x4*)(maskadd + kt * 16 + quad * 4);
                float e0 = fexp2(sc[k8][0] + bv[0] + mv[0]);
                float e1 = fexp2(sc[k8][1] + bv[1] + mv[1]);
                float e2 = fexp2(sc[k8][2] + bv[2] + mv[2]);
                float e3 = fexp2(sc[k8][3] + bv[3] + mv[3]);
                sum += (e0 + e1) + (e2 + e3);
                cw[kt] = u32x2{pk2(e0, e1), pk2(e2, e3)};
            }
            __builtin_amdgcn_sched_barrier(0);  // keep halves separate (reg pressure)
        }

        // gate loads issued BEFORE PV: their latency hides under 16 MFMAs
        const bf16* gp = QG + (size_t)(s * 256 + q0 + lc) * 512 + 256 + h * 32 + quad * 4;
        bf16x4 gv0 = *(const bf16x4*)(gp);
        bf16x4 gv1 = *(const bf16x4*)(gp + 16);

        // PV as O^T = V^T @ P^T.  B-frag for chunk ks needs lane(quad q') to hold
        // P[q=lc][ks*32 + 8q' + j], j=0..7.  Built via 2x2 lane-group transposes:
        // {r0,r2}=pl16swap(pl32swap(c0,c2)), {r1,r3}=pl16swap(pl32swap(c1,c3)).
        f32x4 o0 = {0.f, 0.f, 0.f, 0.f}, o1 = {0.f, 0.f, 0.f, 0.f};
        #pragma unroll
        for (int ks = 0; ks < 8; ++ks) {
            u32 c0 = cw[2 * ks].x,     c1 = cw[2 * ks].y;
            u32 c2 = cw[2 * ks + 1].x, c3 = cw[2 * ks + 1].y;
            u32x2 s02 = __builtin_amdgcn_permlane32_swap(c0, c2, false, false);
            u32x2 s13 = __builtin_amdgcn_permlane32_swap(c1, c3, false, false);
            u32x2 e02 = __builtin_amdgcn_permlane16_swap(s02.x, s02.y, false, false);
            u32x2 e13 = __builtin_amdgcn_permlane16_swap(s13.x, s13.y, false, false);
            u32x4 pw = {e02.x, e13.x, e02.y, e13.y};
            bf16x8 pf = __builtin_bit_cast(bf16x8, pw);
            bf16x8 v0 = *(const bf16x8*)(Vt + lc * 264 + ks * 32 + quad * 8);
            bf16x8 v1 = *(const bf16x8*)(Vt + (16 + lc) * 264 + ks * 32 + quad * 8);
            o0 = MFMA16(v0, pf, o0);
            o1 = MFMA16(v1, pf, o1);
        }

        // row-sum reduce deferred to epilogue (inv only needed here)
        sum += __shfl_xor(sum, 16, 64);
        sum += __shfl_xor(sum, 32, 64);
        const float inv = 1.0f / sum;

        // epilogue: lane holds O^T[d = nt*16 + quad*4 + rr][q = lc]
        const f32x4 bg0 = *(const f32x4*)(b_g + h * 32 + quad * 4);
        const f32x4 bg1 = *(const f32x4*)(b_g + h * 32 + 16 + quad * 4);
        bf16* op = OG + (size_t)(s * 256 + q0 + lc) * 256 + h * 32 + quad * 4;
        #pragma unroll
        for (int nt = 0; nt < 2; ++nt) {
            f32x4 ov = nt ? o1 : o0;
            f32x4 bg = nt ? bg1 : bg0;
            bf16x4 gv = nt ? gv1 : gv0;
            bf16x4 ob;
            #pragma unroll
            for (int rr = 0; rr < 4; ++rr) {
                float g = 1.0f / (1.0f + __expf(-((float)gv[rr] + bg[rr])));
                ob[rr] = (bf16)(ov[rr] * inv * g);
            }
            *(bf16x4*)(op + nt * 16) = ob;
        }
    }
}

// ================= launch =================
extern "C" void kernel_launch(void* const* d_in, const int* in_sizes, int n_in,
                              void* d_out, int out_size, void* d_ws, size_t ws_size,
                              hipStream_t stream)
{
    (void)in_sizes; (void)n_in; (void)out_size; (void)ws_size;
    const float* q    = (const float*)d_in[0];
    const float* kv   = (const float*)d_in[1];
    const float* bias = (const float*)d_in[2];
    const float* mask = (const float*)d_in[3];
    const float* w_q  = (const float*)d_in[4];
    const float* w_k  = (const float*)d_in[5];
    const float* w_v  = (const float*)d_in[6];
    const float* w_g  = (const float*)d_in[7];
    const float* b_g  = (const float*)d_in[8];
    const float* w_o  = (const float*)d_in[9];
    const float* b_o  = (const float*)d_in[10];
    float* out = (float*)d_out;

    char* ws = (char*)d_ws;
    bf16*  qbf   = (bf16*)(ws + 0);           // 16.78 MB  (aliased: OG after proj)
    bf16*  kvbf  = (bf16*)(ws + 16777216);    // 16.78 MB
    bf16*  QG    = (bf16*)(ws + 33554432);    // 33.55 MB  [32768][512] = [Q*norm | G]
    bf16*  KV    = (bf16*)(ws + 67108864);    // 33.55 MB  [32768][512] = [K | V]
    float* biasT = (float*)(ws + 100663296);  //  2.10 MB  [h][q][k] * log2e
    bf16*  Wqg   = (bf16*)(ws + 102760448);   //  0.26 MB
    bf16*  Wkv   = (bf16*)(ws + 103022592);   //  0.26 MB
    bf16*  Wo    = (bf16*)(ws + 103284736);   //  0.13 MB
    bf16*  OG    = qbf;                       // alias: qbf dead after proj_kernel

    prep_kernel<<<1024, 256, 0, stream>>>(q, kv, bias, w_q, w_k, w_v, w_g, w_o,
                                          qbf, kvbf, biasT, Wqg, Wkv, Wo);
    proj_kernel<<<2048, 256, 0, stream>>>(qbf, kvbf, Wqg, Wkv, QG, KV);
    attn_kernel<<<1024, 256, 0, stream>>>(QG, KV, biasT, mask, b_g, OG);
    outproj_kernel<<<512, 256, 0, stream>>>(OG, Wo, b_o, out);
}

// Round 4
// 213.038 us; speedup vs baseline: 1.6490x; 1.0050x over previous
//
#include <hip/hip_runtime.h>

typedef __bf16 bf16;
typedef __bf16 bf16x8 __attribute__((ext_vector_type(8)));
typedef __bf16 bf16x4 __attribute__((ext_vector_type(4)));
typedef float  f32x4  __attribute__((ext_vector_type(4)));
typedef unsigned int u32;
typedef unsigned int u32x2 __attribute__((ext_vector_type(2)));
typedef unsigned int u32x4 __attribute__((ext_vector_type(4)));
typedef unsigned short u16;

#define MFMA16(a, b, c) __builtin_amdgcn_mfma_f32_16x16x32_bf16((a), (b), (c), 0, 0, 0)
#define L2E 1.4426950408889634f

// B=1, S=128, R=256, C=256, H=8, Ca=32.  M = S*R = 32768, K = 256.

// ---- async global->LDS, 16 B per lane (guide §5: width=16) ----
typedef __attribute__((address_space(3))) u32 lds_u32;
typedef const __attribute__((address_space(1))) u32 glob_u32;
__device__ __forceinline__ void gll16(const void* g, void* l) {
    __builtin_amdgcn_global_load_lds((glob_u32*)g, (lds_u32*)l, 16, 0, 0);
}

// pack two f32 -> one u32 of 2 bf16 (lo, hi); compiler emits v_cvt_pk_bf16_f32
__device__ __forceinline__ u32 pk2(float lo, float hi) {
    u16 a = __builtin_bit_cast(u16, (bf16)lo);
    u16 b = __builtin_bit_cast(u16, (bf16)hi);
    return ((u32)b << 16) | (u32)a;
}

// 2^x via v_exp_f32 (log2e pre-folded into scales at prep)
__device__ __forceinline__ float fexp2(float x) {
#if __has_builtin(__builtin_amdgcn_exp2f)
    return __builtin_amdgcn_exp2f(x);
#else
    return exp2f(x);
#endif
}
__device__ __forceinline__ float frcp(float x) {
#if __has_builtin(__builtin_amdgcn_rcpf)
    return __builtin_amdgcn_rcpf(x);
#else
    return 1.0f / x;
#endif
}

// ================= prep: bias transpose + weight transposes only ==============
// (q/kv f32->bf16 conversion is folded into proj's A-staging — saves ~100 MB)
__global__ __launch_bounds__(256) void prep_kernel(
    const float* __restrict__ bias,
    const float* __restrict__ w_q, const float* __restrict__ w_k,
    const float* __restrict__ w_v, const float* __restrict__ w_g,
    const float* __restrict__ w_o, const float* __restrict__ b_g,
    float* __restrict__ biasT,
    bf16* __restrict__ Wqg, bf16* __restrict__ Wkv, bf16* __restrict__ Wo,
    float* __restrict__ b_gL)
{
    // 1/sqrt(32) * log2(e): softmax computed in base-2 (exp2)
    const float norm = 0.17677669529663687f * L2E;
    const int gid = blockIdx.x * 256 + threadIdx.x;
    const int gsz = gridDim.x * 256;

    // biasT[h][q][k] <- bias[q][k][h] * log2e  (coalesced writes)
    for (int u = gid; u < 524288; u += gsz) {
        int h = u >> 16, qq = (u >> 8) & 255, kk = u & 255;
        biasT[u] = bias[(((qq << 8) + kk) << 3) + h] * L2E;
    }
    // Wqg[n][k]: n<256 -> w_q[k][n]*norm ; else w_g[k][n-256]*log2e (gate in base-2)
    for (int u = gid; u < 131072; u += gsz) {
        int n = u >> 8, k = u & 255;
        float v = (n < 256) ? w_q[k * 256 + n] * norm : w_g[k * 256 + (n - 256)] * L2E;
        Wqg[u] = (bf16)v;
    }
    // Wkv[n][k]: n<256 -> w_k[k][n] ; else w_v[k][n-256]
    for (int u = gid; u < 131072; u += gsz) {
        int n = u >> 8, k = u & 255;
        float v = (n < 256) ? w_k[k * 256 + n] : w_v[k * 256 + (n - 256)];
        Wkv[u] = (bf16)v;
    }
    // Wo[n][k] = w_o[k][n]   ([H*Ca][C] -> [C][H*Ca])
    for (int u = gid; u < 65536; u += gsz) {
        int n = u >> 8, k = u & 255;
        Wo[u] = (bf16)w_o[k * 256 + n];
    }
    // b_gL = b_g * log2e
    for (int u = gid; u < 256; u += gsz) b_gL[u] = b_g[u] * L2E;
}

// ================= tiled GEMM core: C[M][ntot] = A[M][256] @ Bw[ntot][256]^T ===
// 128x128 tile, 256 threads (4 waves, each 64x64), BK=32.
// AMODE 0: A bf16, staged via global_load_lds.  AMODE 1: A f32, reg-staged with
// on-the-fly bf16 conversion (fuses the old prep convert pass into the GEMM).
template<int AMODE, bool F32OUT>
__device__ __forceinline__ void gemm_core(
    const void* __restrict__ Ap, const bf16* __restrict__ Bw,
    bf16* __restrict__ Cb, float* __restrict__ Cf, const float* __restrict__ bo,
    int m0, int n0, int ntot)
{
    __shared__ __align__(16) bf16 As[128 * 32];
    __shared__ __align__(16) bf16 Bs[128 * 32];

    const bf16*  A16 = (const bf16*)Ap;
    const float* A32 = (const float*)Ap;

    const int tid  = threadIdx.x;
    const int lane = tid & 63, wave = tid >> 6;
    const int quad = lane >> 4, lc = lane & 15;
    const int wr = wave >> 1, wc = wave & 1;

    const int r0 = tid >> 2, p0 = tid & 3;
    const size_t offA0 = (size_t)(m0 + r0) * 256 + p0 * 8;
    const size_t offA1 = (size_t)(m0 + 64 + r0) * 256 + p0 * 8;
    const bf16* gB0 = Bw + (size_t)(n0 + r0) * 256 + p0 * 8;
    const bf16* gB1 = Bw + (size_t)(n0 + 64 + r0) * 256 + p0 * 8;
    bf16* lA0 = As + tid * 8;
    bf16* lA1 = As + (tid + 256) * 8;
    bf16* lB0 = Bs + tid * 8;
    bf16* lB1 = Bs + (tid + 256) * 8;

    f32x4 acc[4][4];
    #pragma unroll
    for (int i = 0; i < 4; ++i)
        #pragma unroll
        for (int j = 0; j < 4; ++j) acc[i][j] = f32x4{0.f, 0.f, 0.f, 0.f};

    #pragma unroll 1
    for (int kb = 0; kb < 8; ++kb) {
        const int ko = kb * 32;
        if constexpr (AMODE == 0) {
            gll16(A16 + offA0 + ko, lA0);
            gll16(A16 + offA1 + ko, lA1);
            gll16(gB0 + ko, lB0);
            gll16(gB1 + ko, lB1);
        } else {
            // issue all 4 f32 loads first, then B DMA, then converts
            float4 x0 = *(const float4*)(A32 + offA0 + ko);
            float4 x1 = *(const float4*)(A32 + offA0 + ko + 4);
            float4 y0 = *(const float4*)(A32 + offA1 + ko);
            float4 y1 = *(const float4*)(A32 + offA1 + ko + 4);
            gll16(gB0 + ko, lB0);
            gll16(gB1 + ko, lB1);
            bf16x8 ta, tb;
            ta[0]=(bf16)x0.x; ta[1]=(bf16)x0.y; ta[2]=(bf16)x0.z; ta[3]=(bf16)x0.w;
            ta[4]=(bf16)x1.x; ta[5]=(bf16)x1.y; ta[6]=(bf16)x1.z; ta[7]=(bf16)x1.w;
            tb[0]=(bf16)y0.x; tb[1]=(bf16)y0.y; tb[2]=(bf16)y0.z; tb[3]=(bf16)y0.w;
            tb[4]=(bf16)y1.x; tb[5]=(bf16)y1.y; tb[6]=(bf16)y1.z; tb[7]=(bf16)y1.w;
            *(bf16x8*)lA0 = ta;
            *(bf16x8*)lA1 = tb;
        }
        __syncthreads();

        bf16x8 aF[4], bF[4];
        #pragma unroll
        for (int mt = 0; mt < 4; ++mt)
            aF[mt] = *(const bf16x8*)(As + (wr * 64 + mt * 16 + lc) * 32 + quad * 8);
        #pragma unroll
        for (int nt = 0; nt < 4; ++nt)
            bF[nt] = *(const bf16x8*)(Bs + (wc * 64 + nt * 16 + lc) * 32 + quad * 8);
        #pragma unroll
        for (int mt = 0; mt < 4; ++mt)
            #pragma unroll
            for (int nt = 0; nt < 4; ++nt)
                acc[mt][nt] = MFMA16(aF[mt], bF[nt], acc[mt][nt]);
        __syncthreads();
    }

    #pragma unroll
    for (int mt = 0; mt < 4; ++mt) {
        #pragma unroll
        for (int nt = 0; nt < 4; ++nt) {
            const int row = m0 + wr * 64 + mt * 16 + quad * 4;
            const int col = n0 + wc * 64 + nt * 16 + lc;
            if (F32OUT) {
                float b = bo[col];
                #pragma unroll
                for (int rr = 0; rr < 4; ++rr)
                    Cf[(size_t)(row + rr) * ntot + col] = acc[mt][nt][rr] + b;
            } else {
                #pragma unroll
                for (int rr = 0; rr < 4; ++rr)
                    Cb[(size_t)(row + rr) * ntot + col] = (bf16)acc[mt][nt][rr];
            }
        }
    }
}

// Block->tile remap: mi = bid&255 (m-strip), ni = bid>>8.  All ni-variants of an
// A-strip share bid%8 (same XCD) and are ~256 dispatches apart (co-resident) ->
// A-strip read from HBM once, served from that XCD's L2 for the other n-tiles.
__global__ __launch_bounds__(256) void proj_kernel(
    const float* __restrict__ qf, const float* __restrict__ kvf,
    const bf16* __restrict__ Wqg, const bf16* __restrict__ Wkv,
    bf16* __restrict__ QG, bf16* __restrict__ KV)
{
    int bid = blockIdx.x;
    bool sel = bid >= 1024;
    int b = sel ? bid - 1024 : bid;
    int m0 = (b & 255) * 128, n0 = (b >> 8) * 128;
    gemm_core<1, false>(sel ? kvf : qf, sel ? Wkv : Wqg,
                        sel ? KV : QG, nullptr, nullptr, m0, n0, 512);
}

__global__ __launch_bounds__(256) void outproj_kernel(
    const bf16* __restrict__ OG, const bf16* __restrict__ Wo,
    const float* __restrict__ bo, float* __restrict__ out)
{
    int b = blockIdx.x;
    int m0 = (b & 255) * 128, n0 = (b >> 8) * 128;
    gemm_core<0, true>(OG, Wo, nullptr, out, bo, m0, n0, 256);
}

// ================= attention per (s,h): 256 threads, 4 waves ====================
// Swapped QK^T (S^T = mfma(K, Q)): lane owns ONE q-row (q = lc), 64 k's.
// Softmax in-register (base-2, log2e pre-folded); P -> PV B-operand via
// cvt_pk + permlane32_swap + permlane16_swap; never touches LDS.
// QK^T in two 8-kt halves (MFMA 8 -> exp/pack 8) to cap sc live range; fence
// between halves allows VALU/SALU to cross (exp overlaps next MFMA issue) but
// pins MFMA/DS (round-2 lesson: unconstrained -> VGPR 160 -> occupancy cliff;
// round-1 lesson: forcing occupancy via launch_bounds -> scratch spill).
// Block map: h = bid>>7, s = bid&127 -> XCD(bid%8) = s%8: all 8 h's of a row-s
// share one XCD's L2 (QG/KV lines fetched once); biasT 2 MB/XCD fits 4 MB L2.
// LDS: mask[256]f32 @0 | Ks[256][40]bf16 @1024 | Vt[32][264]bf16 @21504
#define A_OFF_MASK 0
#define A_OFF_K    1024
#define A_OFF_VT   21504
#define A_LDS_TOT  (21504 + 32 * 264 * 2)   // 38400 B -> 4 blocks/CU (LDS limit)

__global__ __launch_bounds__(256) void attn_kernel(
    const bf16* __restrict__ QG, const bf16* __restrict__ KV,
    const float* __restrict__ biasT, const float* __restrict__ bias_mask,
    const float* __restrict__ b_gL, bf16* __restrict__ OG)
{
    __shared__ __align__(16) char smem[A_LDS_TOT];
    float* maskadd = (float*)(smem + A_OFF_MASK);
    bf16*  Ks      = (bf16*)(smem + A_OFF_K);
    bf16*  Vt      = (bf16*)(smem + A_OFF_VT);

    const int tid  = threadIdx.x;
    const int wave = tid >> 6, lane = tid & 63;
    const int quad = lane >> 4, lc = lane & 15;
    const int h = blockIdx.x >> 7;       // all h of same s -> same XCD (bid%8 = s%8)
    const int s = blockIdx.x & 127;

    // ---- stage mask, K, V^T ----
    maskadd[tid] = (bias_mask[s * 256 + tid] - 1.0f) * (1e9f * L2E);
    {
        const bf16* kvrow = KV + (size_t)(s * 256 + tid) * 512 + h * 32;
        #pragma unroll
        for (int j = 0; j < 4; ++j)
            *(bf16x8*)(Ks + tid * 40 + j * 8) = *(const bf16x8*)(kvrow + j * 8);
        bf16x8 vx[4];
        #pragma unroll
        for (int j = 0; j < 4; ++j) vx[j] = *(const bf16x8*)(kvrow + 256 + j * 8);
        #pragma unroll
        for (int d = 0; d < 32; ++d)
            Vt[d * 264 + tid] = vx[d >> 3][d & 7];
    }
    __syncthreads();

    // gate bias (base-2 scaled), hoisted
    const f32x4 bg0 = *(const f32x4*)(b_gL + h * 32 + quad * 4);
    const f32x4 bg1 = *(const f32x4*)(b_gL + h * 32 + 16 + quad * 4);

    #pragma unroll 1
    for (int p = 0; p < 4; ++p) {
        const int q0 = (wave * 4 + p) * 16;

        // B-operand Q^T: lane holds Q[q0+lc][quad*8+j]
        bf16x8 qf = *(const bf16x8*)(QG + (size_t)(s * 256 + q0 + lc) * 512 + h * 32 + quad * 8);

        // S^T[k][q] in two 8-kt halves to cap sc live range (VGPR <= 128).
        const float* bT = biasT + (((size_t)h * 256 + q0 + lc) << 8) + quad * 4;
        u32x2 cw[16];
        float sum = 0.f;
        #pragma unroll
        for (int half = 0; half < 2; ++half) {
            f32x4 sc[8];
            #pragma unroll
            for (int k8 = 0; k8 < 8; ++k8) {
                const int kt = half * 8 + k8;
                bf16x8 kf = *(const bf16x8*)(Ks + (kt * 16 + lc) * 40 + quad * 8);
                f32x4 z = {0.f, 0.f, 0.f, 0.f};
                sc[k8] = MFMA16(kf, qf, z);
            }
            #pragma unroll
            for (int k8 = 0; k8 < 8; ++k8) {
                const int kt = half * 8 + k8;
                f32x4 bv = *(const f32x4*)(bT + kt * 16);
                f32x4 mv = *(const f32x4*)(maskadd + kt * 16 + quad * 4);
                f32x4 t = sc[k8] + bv + mv;       // packed f32 adds
                float e0 = fexp2(t[0]);
                float e1 = fexp2(t[1]);
                float e2 = fexp2(t[2]);
                float e3 = fexp2(t[3]);
                sum += (e0 + e1) + (e2 + e3);
                cw[kt] = u32x2{pk2(e0, e1), pk2(e2, e3)};
            }
            // VALU|SALU may cross (exp sinks into next half's MFMA slots);
            // MFMA/DS pinned -> sc live range stays one half.
            __builtin_amdgcn_sched_barrier(0x6);
        }

        // gate loads issued BEFORE PV: their latency hides under 16 MFMAs
        const bf16* gp = QG + (size_t)(s * 256 + q0 + lc) * 512 + 256 + h * 32 + quad * 4;
        bf16x4 gv0 = *(const bf16x4*)(gp);
        bf16x4 gv1 = *(const bf16x4*)(gp + 16);

        // PV as O^T = V^T @ P^T.  B-frag for chunk ks needs lane(quad q') to hold
        // P[q=lc][ks*32 + 8q' + j], j=0..7.  Built via 2x2 lane-group transposes:
        // {r0,r2}=pl16swap(pl32swap(c0,c2)), {r1,r3}=pl16swap(pl32swap(c1,c3)).
        f32x4 o0 = {0.f, 0.f, 0.f, 0.f}, o1 = {0.f, 0.f, 0.f, 0.f};
        #pragma unroll
        for (int ks = 0; ks < 8; ++ks) {
            u32 c0 = cw[2 * ks].x,     c1 = cw[2 * ks].y;
            u32 c2 = cw[2 * ks + 1].x, c3 = cw[2 * ks + 1].y;
            u32x2 s02 = __builtin_amdgcn_permlane32_swap(c0, c2, false, false);
            u32x2 s13 = __builtin_amdgcn_permlane32_swap(c1, c3, false, false);
            u32x2 e02 = __builtin_amdgcn_permlane16_swap(s02.x, s02.y, false, false);
            u32x2 e13 = __builtin_amdgcn_permlane16_swap(s13.x, s13.y, false, false);
            u32x4 pw = {e02.x, e13.x, e02.y, e13.y};
            bf16x8 pf = __builtin_bit_cast(bf16x8, pw);
            bf16x8 v0 = *(const bf16x8*)(Vt + lc * 264 + ks * 32 + quad * 8);
            bf16x8 v1 = *(const bf16x8*)(Vt + (16 + lc) * 264 + ks * 32 + quad * 8);
            o0 = MFMA16(v0, pf, o0);
            o1 = MFMA16(v1, pf, o1);
        }

        // row-sum reduce deferred to epilogue (inv only needed here)
        sum += __shfl_xor(sum, 16, 64);
        sum += __shfl_xor(sum, 32, 64);
        const float inv = frcp(sum);

        // epilogue: lane holds O^T[d = nt*16 + quad*4 + rr][q = lc]
        bf16* op = OG + (size_t)(s * 256 + q0 + lc) * 256 + h * 32 + quad * 4;
        #pragma unroll
        for (int nt = 0; nt < 2; ++nt) {
            f32x4 ov = nt ? o1 : o0;
            f32x4 bg = nt ? bg1 : bg0;
            bf16x4 gv = nt ? gv1 : gv0;
            bf16x4 ob;
            #pragma unroll
            for (int rr = 0; rr < 4; ++rr) {
                float e = fexp2(-((float)gv[rr] + bg[rr]));   // base-2 sigmoid
                float g = frcp(1.0f + e);
                ob[rr] = (bf16)(ov[rr] * (inv * g));
            }
            *(bf16x4*)(op + nt * 16) = ob;
        }
    }
}

// ================= launch =================
extern "C" void kernel_launch(void* const* d_in, const int* in_sizes, int n_in,
                              void* d_out, int out_size, void* d_ws, size_t ws_size,
                              hipStream_t stream)
{
    (void)in_sizes; (void)n_in; (void)out_size; (void)ws_size;
    const float* q    = (const float*)d_in[0];
    const float* kv   = (const float*)d_in[1];
    const float* bias = (const float*)d_in[2];
    const float* mask = (const float*)d_in[3];
    const float* w_q  = (const float*)d_in[4];
    const float* w_k  = (const float*)d_in[5];
    const float* w_v  = (const float*)d_in[6];
    const float* w_g  = (const float*)d_in[7];
    const float* b_g  = (const float*)d_in[8];
    const float* w_o  = (const float*)d_in[9];
    const float* b_o  = (const float*)d_in[10];
    float* out = (float*)d_out;

    char* ws = (char*)d_ws;
    bf16*  OG    = (bf16*)(ws + 0);           // 16.78 MB
    bf16*  QG    = (bf16*)(ws + 33554432);    // 33.55 MB  [32768][512] = [Q*norm | G*l2e]
    bf16*  KV    = (bf16*)(ws + 67108864);    // 33.55 MB  [32768][512] = [K | V]
    float* biasT = (float*)(ws + 100663296);  //  2.10 MB  [h][q][k] * log2e
    bf16*  Wqg   = (bf16*)(ws + 102760448);   //  0.26 MB
    bf16*  Wkv   = (bf16*)(ws + 103022592);   //  0.26 MB
    bf16*  Wo    = (bf16*)(ws + 103284736);   //  0.13 MB
    float* b_gL  = (float*)(ws + 103415808);  //  1 KB     b_g * log2e

    prep_kernel<<<256, 256, 0, stream>>>(bias, w_q, w_k, w_v, w_g, w_o, b_g,
                                         biasT, Wqg, Wkv, Wo, b_gL);
    proj_kernel<<<2048, 256, 0, stream>>>(q, kv, Wqg, Wkv, QG, KV);
    attn_kernel<<<1024, 256, 0, stream>>>(QG, KV, biasT, mask, b_gL, OG);
    outproj_kernel<<<512, 256, 0, stream>>>(OG, Wo, b_o, out);
}